// Round 9
// baseline (91.994 us; speedup 1.0000x reference)
//
#include <hip/hip_runtime.h>

// Sparse submanifold 3D conv via dense bf16 MFMA (32x32x16). Round 9:
//  - R8 bug fixed: the software-pipeline rotate (c=p register copies) could
//    execute while the p-loads were still in flight (v_mov has no interlock
//    with pending buffer_load destinations) -> sporadic stale data. Replaced
//    with a STATIC even/odd double buffer (pa*/pb*): iteration k consumes
//    buffer k&1, loads k+1 into the other; (k&1) folds at unroll time so no
//    register moves exist at all. Every consumer reads the SSA values defined
//    by the s_waitcnt asm ("+v" ties) -> cannot be hoisted above the wait.
//  - LOADQ outputs are earlyclobber ("=&v") so they can't alias voff/rsrc.
//  - Kept from R8: OOB-returning SRSRC gathers (sentinel row n -> HW zeros,
//    TA drops OOB lanes), 1-deep pipeline with vmcnt(4), no compiler VMEM
//    inside the k-loop.
//  - Kept from R5-R7: XCD-contiguous swizzle, conflict-free fragment-ordered
//    W->LDS prologue (108 KiB), register-preloaded nbr, static acc indexing.

typedef short          bf16x8 __attribute__((ext_vector_type(8)));
typedef unsigned short u16x8  __attribute__((ext_vector_type(8)));
typedef float          f32x16 __attribute__((ext_vector_type(16)));
typedef float          f32x4a __attribute__((ext_vector_type(4)));
typedef int            i32x4  __attribute__((ext_vector_type(4)));
typedef int            i32x4u __attribute__((ext_vector_type(4), aligned(4)));
typedef int            i32x2u __attribute__((ext_vector_type(2), aligned(4)));

constexpr int CIN   = 32;
constexpr int COUT  = 64;
constexpr int KV    = 27;
constexpr int WAVES = 16;
constexpr int RPW   = 32;              // rows per wave (one 32x32 tile)
constexpr int RPB   = WAVES * RPW;     // 512 rows per block
constexpr int NFRAG = KV * 4;          // B fragments (k * {ci-chunk} * {co-half})
constexpr int SLOTS = NFRAG * 64;      // 6912 b128 LDS slots

// 4 x buffer_load_dwordx4: one lane's 64B share of a feature row
// (ci chunk0 at voff+0/16, chunk1 at voff+64/80). OOB lanes return 0.
// Outputs earlyclobber: must not alias voff/rsrc (loads complete async).
#define LOADQ(g0, g1, g2, g3, voff, rs)                                   \
    asm volatile("buffer_load_dwordx4 %0, %4, %5, 0 offen offset:0\n\t"   \
                 "buffer_load_dwordx4 %1, %4, %5, 0 offen offset:16\n\t"  \
                 "buffer_load_dwordx4 %2, %4, %5, 0 offen offset:64\n\t"  \
                 "buffer_load_dwordx4 %3, %4, %5, 0 offen offset:80"      \
                 : "=&v"(g0), "=&v"(g1), "=&v"(g2), "=&v"(g3)             \
                 : "v"(voff), "s"(rs))

// counted waits, data-tied to the stage registers so dependent VALU/MFMA
// cannot be hoisted above them (rule #18 via data deps)
#define WAITV4(a, b, c, d) \
    asm volatile("s_waitcnt vmcnt(4)" : "+v"(a), "+v"(b), "+v"(c), "+v"(d))
#define WAITV0(a, b, c, d) \
    asm volatile("s_waitcnt vmcnt(0)" : "+v"(a), "+v"(b), "+v"(c), "+v"(d))

__device__ inline bf16x8 cvt8(f32x4a lo, f32x4a hi) {
    bf16x8 r;
#pragma unroll
    for (int j = 0; j < 4; ++j) {
        r[j]     = __builtin_bit_cast(short, (__bf16)lo[j]);
        r[4 + j] = __builtin_bit_cast(short, (__bf16)hi[j]);
    }
    return r;
}

// static-index accessor into the preloaded nbr registers (folds after unroll)
#define NIDX(A, B, C, k) ((k) < 24 ? (A)[(k) >> 2][(k) & 3] \
                                   : ((k) < 26 ? (B)[(k) - 24] : (C)))

__global__ __launch_bounds__(1024, 4)
void spconv_mfma_kernel(const float* __restrict__ feats,
                        const float* __restrict__ weight,
                        const float* __restrict__ bias,
                        const int*   __restrict__ nbr,
                        float*       __restrict__ out,
                        int n, int nwg)
{
    // B fragments: frag = k*4 + cc*2 + h (cc = ci>>4 chunk, h = co>>5 half).
    // Lane holds 8 bf16 at halfword offset frag*512 + lane*8:
    //   col(co within half) = lane&31, kk = 8*(lane>>5) + j.
    __shared__ __align__(16) unsigned short wlds[NFRAG * 512];  // 108 KiB

    const int tid  = threadIdx.x;
    const int lane = tid & 63;
    const int wv   = tid >> 6;
    const int l31  = lane & 31;
    const int e5   = lane >> 5;

    // ---- prologue: W (f32 [k][ci][co]) -> LDS bf16, one fragment per
    //      wave-iteration, linear b128 writes (conflict-free) ----
#pragma unroll
    for (int i = 0; i < 7; ++i) {
        const int s = tid + 1024 * i;          // b128 slot = frag*64 + ln
        if (s < SLOTS) {
            const int frag = s >> 6;           // wave-uniform (frag = wv + 16*i)
            const int ln   = s & 63;
            const int k    = frag >> 2;
            const int cc   = (frag >> 1) & 1;
            const int h    = frag & 1;
            const int co   = (ln & 31) + (h << 5);
            const int cib  = (cc << 4) + ((ln >> 5) << 3);
            const float* src = weight + k * 2048 + cib * 64 + co;
            u16x8 t;
#pragma unroll
            for (int j = 0; j < 8; ++j)
                t[j] = __builtin_bit_cast(unsigned short, (__bf16)src[j * 64]);
            *(u16x8*)&wlds[s * 8] = t;         // ds_write_b128, stride 16B
        }
    }
    __syncthreads();

    // ---- XCD-contiguous block swizzle (bijective for any nwg) ----
    const int q    = nwg >> 3, r = nwg & 7;
    const int xcd  = blockIdx.x & 7, bidx = blockIdx.x >> 3;
    const int wg   = (xcd < r ? xcd * (q + 1) : r * (q + 1) + (xcd - r) * q) + bidx;

    const int rb = wg * RPB + wv * RPW;
    if (rb >= n) return;                       // wave-uniform, after the barrier

    // ---- SRSRC for features: num_records = n rows * 128 B; sentinel row n
    //      and anything past it is OOB -> HW returns 0 ----
    i32x4 rsrc;
    rsrc.x = (int)(unsigned)(uintptr_t)feats;
    rsrc.y = (int)((uintptr_t)feats >> 32);    // stride=0
    rsrc.z = n * (int)(CIN * sizeof(float));   // num_records in bytes
    rsrc.w = 0x00020000;                       // raw dword access

    // ---- preload all 27 neighbor indices for this lane's row ----
    const int  row = rb + l31;                 // lanes r and r+32 share a row
    const bool rv  = row < n;
    const int* p   = nbr + (size_t)min(row, n - 1) * KV;
    i32x4u nA[6]; i32x2u nB; int nC;
#pragma unroll
    for (int qq = 0; qq < 6; ++qq) nA[qq] = *(const i32x4u*)(p + 4 * qq);
    nB = *(const i32x2u*)(p + 24);
    nC = p[26];
    if (!rv) {                                 // clamped rows: force sentinel
#pragma unroll
        for (int qq = 0; qq < 6; ++qq) nA[qq] = i32x4u{n, n, n, n};
        nB = i32x2u{n, n};
        nC = n;
    }

    f32x16 acc0 = {}, acc1 = {};               // co-halves 0 / 1

#define GATHER_K(kk, B0, B1, B2, B3)                                      \
    do {                                                                  \
        const int voff_ = (NIDX(nA, nB, nC, (kk)) << 7) + (e5 << 5);      \
        LOADQ(B0, B1, B2, B3, voff_, rsrc);                               \
    } while (0)

    // ---- 1-deep pipelined, fully-unrolled k-loop; even/odd static buffers,
    //      ZERO register moves (buffer choice folds at unroll time) ----
    f32x4a pa0, pa1, pa2, pa3, pb0, pb1, pb2, pb3;
    GATHER_K(0, pa0, pa1, pa2, pa3);           // k=0 data -> buffer A
#pragma unroll
    for (int k = 0; k < KV; ++k) {
        // B fragments first: independent lgkm loads can issue before the wait
        const int fb = (k << 2) * 512 + lane * 8;
        const bf16x8 b00 = *(const bf16x8*)&wlds[fb];
        const bf16x8 b01 = *(const bf16x8*)&wlds[fb + 512];
        const bf16x8 b10 = *(const bf16x8*)&wlds[fb + 1024];
        const bf16x8 b11 = *(const bf16x8*)&wlds[fb + 1536];

        bf16x8 x0, x1;
        if ((k & 1) == 0) {                    // data in A; prefetch into B
            if (k + 1 < KV) {
                GATHER_K(k + 1, pb0, pb1, pb2, pb3);   // 8 outstanding
                WAITV4(pa0, pa1, pa2, pa3);            // A's 4 retired
            } else {
                WAITV0(pa0, pa1, pa2, pa3);
            }
            x0 = cvt8(pa0, pa1); x1 = cvt8(pa2, pa3);
        } else {                               // data in B; prefetch into A
            if (k + 1 < KV) {
                GATHER_K(k + 1, pa0, pa1, pa2, pa3);
                WAITV4(pb0, pb1, pb2, pb3);
            } else {
                WAITV0(pb0, pb1, pb2, pb3);
            }
            x0 = cvt8(pb0, pb1); x1 = cvt8(pb2, pb3);
        }

        acc0 = __builtin_amdgcn_mfma_f32_32x32x16_bf16(x0, b00, acc0, 0, 0, 0);
        acc1 = __builtin_amdgcn_mfma_f32_32x32x16_bf16(x0, b01, acc1, 0, 0, 0);
        acc0 = __builtin_amdgcn_mfma_f32_32x32x16_bf16(x1, b10, acc0, 0, 0, 0);
        acc1 = __builtin_amdgcn_mfma_f32_32x32x16_bf16(x1, b11, acc1, 0, 0, 0);
    }
#undef GATHER_K

    // ---- epilogue: C/D layout col=lane&31, row=(t&3)+8*(t>>2)+4*e5 ----
    const float bb0 = bias[l31];
    const float bb1 = bias[l31 + 32];
#pragma unroll
    for (int t = 0; t < 16; ++t) {
        const int rr   = (t & 3) + ((t >> 2) << 3) + (e5 << 2);
        const int orow = rb + rr;
        if (orow < n) {
            out[(size_t)orow * COUT + l31]      = acc0[t] + bb0;
            out[(size_t)orow * COUT + l31 + 32] = acc1[t] + bb1;
        }
    }
}

extern "C" void kernel_launch(void* const* d_in, const int* in_sizes, int n_in,
                              void* d_out, int out_size, void* d_ws, size_t ws_size,
                              hipStream_t stream)
{
    const float* feats  = (const float*)d_in[0];   // (N, 32) f32
    const float* weight = (const float*)d_in[1];   // (27, 32, 64) f32
    const float* bias   = (const float*)d_in[2];   // (64,) f32
    const int*   nbr    = (const int*)  d_in[3];   // (N, 27) i32, sentinel = N

    float* out = (float*)d_out;                    // (N, 64) f32

    const int n   = in_sizes[0] / CIN;
    const int nwg = (n + RPB - 1) / RPB;

    spconv_mfma_kernel<<<dim3(nwg), dim3(1024), 0, stream>>>(
        feats, weight, bias, nbr, out, n, nwg);
}

// Round 10
// 83.302 us; speedup vs baseline: 1.1043x; 1.1043x over previous
//
#include <hip/hip_runtime.h>

// Sparse submanifold 3D conv via dense bf16 MFMA (32x32x16). Round 10:
//  - BF16 FEATURE PRE-PASS into d_ws (~12us memory-bound): hot-loop gathers
//    become 2 x buffer_load_dwordx4 (32B/lane-k instead of 64B) and the
//    loaded 16B ARE the MFMA A-fragments -> the 16 cvt VALU ops per k
//    disappear; TA instrs and gather L2 bytes halve; XCD gather working set
//    halves (~1.3MB, L2-resident).
//  - PIPELINE DEPTH 3 (R9's depth-1 gave 0 gain: one ~100cyc k-body can't
//    hide ~200-400cyc L2 latency). Prologue loads k=0..2; body issues k+3
//    then vmcnt(6); tail drains 4->2->0. Four static mod-4 register stages,
//    zero moves (R8 lesson), all waits data-tied ("+v").
//  - OOB-returning SRSRC (num_records = n*64): sentinel row n -> HW zeros.
//  - Kept: XCD-contiguous swizzle, conflict-free fragment-ordered W->LDS
//    prologue (108 KiB), register-preloaded nbr, static acc indexing.
//  - Fallback (ws too small): R9 kernel (f32 gathers, depth-1), verified.

typedef short          bf16x8 __attribute__((ext_vector_type(8)));
typedef unsigned short u16x8  __attribute__((ext_vector_type(8)));
typedef float          f32x16 __attribute__((ext_vector_type(16)));
typedef float          f32x4a __attribute__((ext_vector_type(4)));
typedef int            i32x4  __attribute__((ext_vector_type(4)));
typedef int            i32x4u __attribute__((ext_vector_type(4), aligned(4)));
typedef int            i32x2u __attribute__((ext_vector_type(2), aligned(4)));

constexpr int CIN   = 32;
constexpr int COUT  = 64;
constexpr int KV    = 27;
constexpr int WAVES = 16;
constexpr int RPW   = 32;              // rows per wave (one 32x32 tile)
constexpr int RPB   = WAVES * RPW;     // 512 rows per block
constexpr int NFRAG = KV * 4;          // B fragments (k * {ci-chunk} * {co-half})
constexpr int SLOTS = NFRAG * 64;      // 6912 b128 LDS slots

// ---- asm helpers ----
// 2 x buffer_load_dwordx4: one lane's 32B (16 bf16) share of a feature row.
// chunk0 (ci 0..15) at voff+0, chunk1 (ci 16..31) at voff+32. OOB -> 0.
#define LOADD(g0, g1, voff, rs)                                           \
    asm volatile("buffer_load_dwordx4 %0, %2, %3, 0 offen offset:0\n\t"   \
                 "buffer_load_dwordx4 %1, %2, %3, 0 offen offset:32"      \
                 : "=&v"(g0), "=&v"(g1)                                   \
                 : "v"(voff), "s"(rs))
// counted waits, data-tied to the consumed stage registers (no hoisting)
#define WAIT6(a, b) asm volatile("s_waitcnt vmcnt(6)" : "+v"(a), "+v"(b))
#define WAIT4(a, b) asm volatile("s_waitcnt vmcnt(4)" : "+v"(a), "+v"(b))
#define WAIT2(a, b) asm volatile("s_waitcnt vmcnt(2)" : "+v"(a), "+v"(b))
#define WAIT0(a, b) asm volatile("s_waitcnt vmcnt(0)" : "+v"(a), "+v"(b))

// f32 variant (fallback kernel)
#define LOADQ(g0, g1, g2, g3, voff, rs)                                   \
    asm volatile("buffer_load_dwordx4 %0, %4, %5, 0 offen offset:0\n\t"   \
                 "buffer_load_dwordx4 %1, %4, %5, 0 offen offset:16\n\t"  \
                 "buffer_load_dwordx4 %2, %4, %5, 0 offen offset:64\n\t"  \
                 "buffer_load_dwordx4 %3, %4, %5, 0 offen offset:80"      \
                 : "=&v"(g0), "=&v"(g1), "=&v"(g2), "=&v"(g3)             \
                 : "v"(voff), "s"(rs))
#define WAITV4(a, b, c, d) \
    asm volatile("s_waitcnt vmcnt(4)" : "+v"(a), "+v"(b), "+v"(c), "+v"(d))
#define WAITV0(a, b, c, d) \
    asm volatile("s_waitcnt vmcnt(0)" : "+v"(a), "+v"(b), "+v"(c), "+v"(d))

__device__ inline bf16x8 cvt8(f32x4a lo, f32x4a hi) {
    bf16x8 r;
#pragma unroll
    for (int j = 0; j < 4; ++j) {
        r[j]     = __builtin_bit_cast(short, (__bf16)lo[j]);
        r[4 + j] = __builtin_bit_cast(short, (__bf16)hi[j]);
    }
    return r;
}

// static-index accessor into the preloaded nbr registers (folds after unroll)
#define NIDX(A, B, C, k) ((k) < 24 ? (A)[(k) >> 2][(k) & 3] \
                                   : ((k) < 26 ? (B)[(k) - 24] : (C)))

// ---- pre-pass: features f32 -> bf16 into workspace ----
__global__ __launch_bounds__(256)
void feats_to_bf16(const float* __restrict__ in,
                   unsigned short* __restrict__ outp, int ngroups)
{
    int i = blockIdx.x * 256 + threadIdx.x;
    const int stride = gridDim.x * 256;
    for (; i < ngroups; i += stride) {
        const f32x4a a = *(const f32x4a*)(in + (size_t)i * 8);
        const f32x4a b = *(const f32x4a*)(in + (size_t)i * 8 + 4);
        u16x8 t;
#pragma unroll
        for (int j = 0; j < 4; ++j) {
            t[j]     = __builtin_bit_cast(unsigned short, (__bf16)a[j]);
            t[4 + j] = __builtin_bit_cast(unsigned short, (__bf16)b[j]);
        }
        *(u16x8*)(outp + (size_t)i * 8) = t;
    }
}

// ---- shared building blocks (both kernels) ----
#define W_PROLOGUE()                                                        \
    do {                                                                    \
        _Pragma("unroll")                                                   \
        for (int i = 0; i < 7; ++i) {                                       \
            const int s = tid + 1024 * i;                                   \
            if (s < SLOTS) {                                                \
                const int frag = s >> 6;                                    \
                const int ln   = s & 63;                                    \
                const int k    = frag >> 2;                                 \
                const int cc   = (frag >> 1) & 1;                           \
                const int h    = frag & 1;                                  \
                const int co   = (ln & 31) + (h << 5);                      \
                const int cib  = (cc << 4) + ((ln >> 5) << 3);              \
                const float* src = weight + k * 2048 + cib * 64 + co;       \
                u16x8 t;                                                    \
                _Pragma("unroll")                                           \
                for (int j = 0; j < 8; ++j)                                 \
                    t[j] = __builtin_bit_cast(unsigned short,               \
                                              (__bf16)src[j * 64]);         \
                *(u16x8*)&wlds[s * 8] = t;                                  \
            }                                                               \
        }                                                                   \
    } while (0)

#define NBR_PRELOAD()                                                       \
    i32x4u nA[6]; i32x2u nB; int nC;                                        \
    do {                                                                    \
        const int* p = nbr + (size_t)min(row, n - 1) * KV;                  \
        _Pragma("unroll")                                                   \
        for (int qq = 0; qq < 6; ++qq) nA[qq] = *(const i32x4u*)(p + 4*qq); \
        nB = *(const i32x2u*)(p + 24);                                      \
        nC = p[26];                                                         \
        if (!rv) {                                                          \
            _Pragma("unroll")                                               \
            for (int qq = 0; qq < 6; ++qq) nA[qq] = i32x4u{n, n, n, n};     \
            nB = i32x2u{n, n};                                              \
            nC = n;                                                         \
        }                                                                   \
    } while (0)

#define EPILOGUE()                                                          \
    do {                                                                    \
        const float bb0 = bias[l31];                                        \
        const float bb1 = bias[l31 + 32];                                   \
        _Pragma("unroll")                                                   \
        for (int t = 0; t < 16; ++t) {                                      \
            const int rr   = (t & 3) + ((t >> 2) << 3) + (e5 << 2);         \
            const int orow = rb + rr;                                       \
            if (orow < n) {                                                 \
                out[(size_t)orow * COUT + l31]      = acc0[t] + bb0;        \
                out[(size_t)orow * COUT + l31 + 32] = acc1[t] + bb1;        \
            }                                                               \
        }                                                                   \
    } while (0)

// ---- main kernel: bf16 gathers, depth-3 pipeline ----
__global__ __launch_bounds__(1024, 4)
void spconv_mfma_bf16(const unsigned short* __restrict__ fbf16,
                      const float* __restrict__ weight,
                      const float* __restrict__ bias,
                      const int*   __restrict__ nbr,
                      float*       __restrict__ out,
                      int n, int nwg)
{
    __shared__ __align__(16) unsigned short wlds[NFRAG * 512];  // 108 KiB

    const int tid  = threadIdx.x;
    const int lane = tid & 63;
    const int wv   = tid >> 6;
    const int l31  = lane & 31;
    const int e5   = lane >> 5;

    W_PROLOGUE();
    __syncthreads();

    const int q    = nwg >> 3, r = nwg & 7;
    const int xcd  = blockIdx.x & 7, bidx = blockIdx.x >> 3;
    const int wg   = (xcd < r ? xcd * (q + 1) : r * (q + 1) + (xcd - r) * q) + bidx;

    const int rb = wg * RPB + wv * RPW;
    if (rb >= n) return;

    // SRSRC over bf16 features: 64 B/row; sentinel row n -> OOB -> zeros
    i32x4 rsrc;
    rsrc.x = (int)(unsigned)(uintptr_t)fbf16;
    rsrc.y = (int)((uintptr_t)fbf16 >> 32);
    rsrc.z = n * (int)(CIN * sizeof(unsigned short));
    rsrc.w = 0x00020000;

    const int  row = rb + l31;
    const bool rv  = row < n;
    NBR_PRELOAD();

    f32x16 acc0 = {}, acc1 = {};

#define GK(kk, P0, P1)                                                     \
    do {                                                                   \
        const int vo_ = (NIDX(nA, nB, nC, (kk)) << 6) + (e5 << 4);         \
        LOADD(P0, P1, vo_, rsrc);                                          \
    } while (0)

    // 4 static stages (mod-4); lane's 16B load IS the A-fragment
    bf16x8 A0a, A0b, A1a, A1b, A2a, A2b, A3a, A3b;
    GK(0, A0a, A0b);
    GK(1, A1a, A1b);
    GK(2, A2a, A2b);

#define KSTEP(CA, CB, PA, PB)                                              \
    do {                                                                   \
        if (k + 3 < KV)       { GK(k + 3, PA, PB); WAIT6(CA, CB); }        \
        else if (k + 3 == KV) { WAIT4(CA, CB); }                           \
        else if (k + 2 == KV) { WAIT2(CA, CB); }                           \
        else                  { WAIT0(CA, CB); }                           \
    } while (0)

#pragma unroll
    for (int k = 0; k < KV; ++k) {
        // B fragments first: independent lgkm loads issue before the wait
        const int fb = (k << 2) * 512 + lane * 8;
        const bf16x8 b00 = *(const bf16x8*)&wlds[fb];
        const bf16x8 b01 = *(const bf16x8*)&wlds[fb + 512];
        const bf16x8 b10 = *(const bf16x8*)&wlds[fb + 1024];
        const bf16x8 b11 = *(const bf16x8*)&wlds[fb + 1536];

        bf16x8 x0, x1;
        if ((k & 3) == 0)      { KSTEP(A0a, A0b, A3a, A3b); x0 = A0a; x1 = A0b; }
        else if ((k & 3) == 1) { KSTEP(A1a, A1b, A0a, A0b); x0 = A1a; x1 = A1b; }
        else if ((k & 3) == 2) { KSTEP(A2a, A2b, A1a, A1b); x0 = A2a; x1 = A2b; }
        else                   { KSTEP(A3a, A3b, A2a, A2b); x0 = A3a; x1 = A3b; }

        acc0 = __builtin_amdgcn_mfma_f32_32x32x16_bf16(x0, b00, acc0, 0, 0, 0);
        acc1 = __builtin_amdgcn_mfma_f32_32x32x16_bf16(x0, b01, acc1, 0, 0, 0);
        acc0 = __builtin_amdgcn_mfma_f32_32x32x16_bf16(x1, b10, acc0, 0, 0, 0);
        acc1 = __builtin_amdgcn_mfma_f32_32x32x16_bf16(x1, b11, acc1, 0, 0, 0);
    }
#undef KSTEP
#undef GK

    EPILOGUE();
}

// ---- fallback kernel (R9, verified): f32 gathers, depth-1 ----
__global__ __launch_bounds__(1024, 4)
void spconv_mfma_f32g(const float* __restrict__ feats,
                      const float* __restrict__ weight,
                      const float* __restrict__ bias,
                      const int*   __restrict__ nbr,
                      float*       __restrict__ out,
                      int n, int nwg)
{
    __shared__ __align__(16) unsigned short wlds[NFRAG * 512];  // 108 KiB

    const int tid  = threadIdx.x;
    const int lane = tid & 63;
    const int wv   = tid >> 6;
    const int l31  = lane & 31;
    const int e5   = lane >> 5;

    W_PROLOGUE();
    __syncthreads();

    const int q    = nwg >> 3, r = nwg & 7;
    const int xcd  = blockIdx.x & 7, bidx = blockIdx.x >> 3;
    const int wg   = (xcd < r ? xcd * (q + 1) : r * (q + 1) + (xcd - r) * q) + bidx;

    const int rb = wg * RPB + wv * RPW;
    if (rb >= n) return;

    i32x4 rsrc;
    rsrc.x = (int)(unsigned)(uintptr_t)feats;
    rsrc.y = (int)((uintptr_t)feats >> 32);
    rsrc.z = n * (int)(CIN * sizeof(float));
    rsrc.w = 0x00020000;

    const int  row = rb + l31;
    const bool rv  = row < n;
    NBR_PRELOAD();

    f32x16 acc0 = {}, acc1 = {};

#define GATHER_K(kk, B0, B1, B2, B3)                                      \
    do {                                                                  \
        const int voff_ = (NIDX(nA, nB, nC, (kk)) << 7) + (e5 << 5);      \
        LOADQ(B0, B1, B2, B3, voff_, rsrc);                               \
    } while (0)

    f32x4a pa0, pa1, pa2, pa3, pb0, pb1, pb2, pb3;
    GATHER_K(0, pa0, pa1, pa2, pa3);
#pragma unroll
    for (int k = 0; k < KV; ++k) {
        const int fb = (k << 2) * 512 + lane * 8;
        const bf16x8 b00 = *(const bf16x8*)&wlds[fb];
        const bf16x8 b01 = *(const bf16x8*)&wlds[fb + 512];
        const bf16x8 b10 = *(const bf16x8*)&wlds[fb + 1024];
        const bf16x8 b11 = *(const bf16x8*)&wlds[fb + 1536];

        bf16x8 x0, x1;
        if ((k & 1) == 0) {
            if (k + 1 < KV) { GATHER_K(k + 1, pb0, pb1, pb2, pb3); WAITV4(pa0, pa1, pa2, pa3); }
            else            { WAITV0(pa0, pa1, pa2, pa3); }
            x0 = cvt8(pa0, pa1); x1 = cvt8(pa2, pa3);
        } else {
            if (k + 1 < KV) { GATHER_K(k + 1, pa0, pa1, pa2, pa3); WAITV4(pb0, pb1, pb2, pb3); }
            else            { WAITV0(pb0, pb1, pb2, pb3); }
            x0 = cvt8(pb0, pb1); x1 = cvt8(pb2, pb3);
        }

        acc0 = __builtin_amdgcn_mfma_f32_32x32x16_bf16(x0, b00, acc0, 0, 0, 0);
        acc1 = __builtin_amdgcn_mfma_f32_32x32x16_bf16(x0, b01, acc1, 0, 0, 0);
        acc0 = __builtin_amdgcn_mfma_f32_32x32x16_bf16(x1, b10, acc0, 0, 0, 0);
        acc1 = __builtin_amdgcn_mfma_f32_32x32x16_bf16(x1, b11, acc1, 0, 0, 0);
    }
#undef GATHER_K

    EPILOGUE();
}

extern "C" void kernel_launch(void* const* d_in, const int* in_sizes, int n_in,
                              void* d_out, int out_size, void* d_ws, size_t ws_size,
                              hipStream_t stream)
{
    const float* feats  = (const float*)d_in[0];   // (N, 32) f32
    const float* weight = (const float*)d_in[1];   // (27, 32, 64) f32
    const float* bias   = (const float*)d_in[2];   // (64,) f32
    const int*   nbr    = (const int*)  d_in[3];   // (N, 27) i32, sentinel = N

    float* out = (float*)d_out;                    // (N, 64) f32

    const int n   = in_sizes[0] / CIN;
    const int nwg = (n + RPB - 1) / RPB;

    const size_t need = (size_t)n * CIN * sizeof(unsigned short);
    if (ws_size >= need) {
        unsigned short* fbf16 = (unsigned short*)d_ws;
        const int ngroups = n * CIN / 8;
        feats_to_bf16<<<dim3(2048), dim3(256), 0, stream>>>(feats, fbf16, ngroups);
        spconv_mfma_bf16<<<dim3(nwg), dim3(1024), 0, stream>>>(
            fbf16, weight, bias, nbr, out, n, nwg);
    } else {
        spconv_mfma_f32g<<<dim3(nwg), dim3(1024), 0, stream>>>(
            feats, weight, bias, nbr, out, n, nwg);
    }
}